// Round 1
// baseline (2628.983 us; speedup 1.0000x reference)
//
#include <hip/hip_runtime.h>
#include <hip/hip_bf16.h>
#include <cstddef>

typedef __bf16 bf16_t;
typedef __bf16 bf16x8 __attribute__((ext_vector_type(8)));
typedef __bf16 bf16x4 __attribute__((ext_vector_type(4)));
typedef float f32x4 __attribute__((ext_vector_type(4)));

#define T_LEN 96
#define BATCH 64
#define DM 1024
#define NTB 6144  // T*B

__device__ __forceinline__ float sigmoidf_(float x) { return 1.0f / (1.0f + expf(-x)); }

// ---------------- LN2 stats: per (tensor i, batch b) mean & inv-std over T*DM ----------------
__global__ __launch_bounds__(256) void ln_stats_kernel(
    const float* __restrict__ r1, const float* __restrict__ r2,
    const float* __restrict__ r3, const float* __restrict__ r4,
    float* __restrict__ stats)  // [4*64][2]
{
    const int i = blockIdx.x >> 6, b = blockIdx.x & 63;
    const float* r = (i == 0) ? r1 : (i == 1) ? r2 : (i == 2) ? r3 : r4;
    float s = 0.f, ss = 0.f;
    for (int t = 0; t < T_LEN; ++t) {
        float4 v = ((const float4*)(r + (size_t)(t * BATCH + b) * DM))[threadIdx.x];
        s  += v.x + v.y + v.z + v.w;
        ss += v.x * v.x + v.y * v.y + v.z * v.z + v.w * v.w;
    }
    __shared__ float sh[512];
    sh[threadIdx.x] = s; sh[256 + threadIdx.x] = ss;
    __syncthreads();
    for (int off = 128; off > 0; off >>= 1) {
        if (threadIdx.x < off) {
            sh[threadIdx.x] += sh[threadIdx.x + off];
            sh[256 + threadIdx.x] += sh[256 + threadIdx.x + off];
        }
        __syncthreads();
    }
    if (threadIdx.x == 0) {
        const float inv = 1.0f / (float)(T_LEN * DM);
        float mean = sh[0] * inv;
        float var  = sh[256] * inv - mean * mean;
        stats[blockIdx.x * 2 + 0] = mean;
        stats[blockIdx.x * 2 + 1] = rsqrtf(var + 1e-5f);
    }
}

// ---------------- U = mean of 4 normalized tensors, written as bf16 [NTB,1024] ----------------
__global__ __launch_bounds__(256) void compute_u_kernel(
    const float* __restrict__ r1, const float* __restrict__ r2,
    const float* __restrict__ r3, const float* __restrict__ r4,
    const float* __restrict__ stats, bf16_t* __restrict__ U)
{
    const int idx4 = blockIdx.x * 256 + threadIdx.x;   // over NTB*1024/4
    const int b = (idx4 >> 8) & 63;                    // row = idx4/256, b = row&63
    const float m0 = stats[(0 * 64 + b) * 2], s0 = stats[(0 * 64 + b) * 2 + 1];
    const float m1 = stats[(1 * 64 + b) * 2], s1 = stats[(1 * 64 + b) * 2 + 1];
    const float m2 = stats[(2 * 64 + b) * 2], s2 = stats[(2 * 64 + b) * 2 + 1];
    const float m3 = stats[(3 * 64 + b) * 2], s3 = stats[(3 * 64 + b) * 2 + 1];
    float4 a = ((const float4*)r1)[idx4];
    float4 c = ((const float4*)r2)[idx4];
    float4 d = ((const float4*)r3)[idx4];
    float4 e = ((const float4*)r4)[idx4];
    bf16x4 o;
    o[0] = (bf16_t)(0.25f * ((a.x - m0) * s0 + (c.x - m1) * s1 + (d.x - m2) * s2 + (e.x - m3) * s3));
    o[1] = (bf16_t)(0.25f * ((a.y - m0) * s0 + (c.y - m1) * s1 + (d.y - m2) * s2 + (e.y - m3) * s3));
    o[2] = (bf16_t)(0.25f * ((a.z - m0) * s0 + (c.z - m1) * s1 + (d.z - m2) * s2 + (e.z - m3) * s3));
    o[3] = (bf16_t)(0.25f * ((a.w - m0) * s0 + (c.w - m1) * s1 + (d.w - m2) * s2 + (e.w - m3) * s3));
    ((bf16x4*)U)[idx4] = o;
}

// ---------------- f32 -> bf16 cast with optional K padding ----------------
__global__ __launch_bounds__(256) void cast_pad_kernel(
    const float* __restrict__ src, bf16_t* __restrict__ dst,
    int rows, int K, int Kpad)
{
    int idx = blockIdx.x * 256 + threadIdx.x;
    if (idx >= rows * Kpad) return;
    int r = idx / Kpad;
    int k = idx - r * Kpad;
    float v = (k < K) ? src[(size_t)r * K + k] : 0.f;
    dst[idx] = (bf16_t)v;
}

// ---------------- bf16 MFMA GEMM: C[M,N] = A[M,K] @ W[N,K]^T + bias ----------------
// 128x128 block tile, BK=32, 4 waves each computing 64x64 (4x4 tiles of 16x16x32).
#define GLDP 40  // LDS row pitch in bf16 (32 + 8 pad)
__global__ __launch_bounds__(256) void gemm_bt_kernel(
    const bf16_t* __restrict__ A, const bf16_t* __restrict__ W,
    const float* __restrict__ bias0, const float* __restrict__ bias1,
    int K, float* __restrict__ outF, bf16_t* __restrict__ outB,
    int ldo, int permute)
{
    __shared__ bf16_t As[128 * GLDP];
    __shared__ bf16_t Bs[128 * GLDP];
    const int tid = threadIdx.x;
    const int lane = tid & 63;
    const int wid = tid >> 6;
    const int q = lane >> 4, l15 = lane & 15;
    const int wr = (wid >> 1) * 64, wc = (wid & 1) * 64;
    const size_t br = (size_t)blockIdx.y * 128;
    const size_t bc = (size_t)blockIdx.x * 128;

    const int r0 = tid >> 2;              // rows 0..63
    const int r1 = r0 + 64;               // rows 64..127
    const int k0 = (tid & 3) * 8;

    f32x4 acc[4][4] = {};

    for (int kt = 0; kt < K; kt += 32) {
        bf16x8 a0 = *(const bf16x8*)(A + (br + r0) * K + kt + k0);
        bf16x8 a1 = *(const bf16x8*)(A + (br + r1) * K + kt + k0);
        bf16x8 w0 = *(const bf16x8*)(W + (bc + r0) * K + kt + k0);
        bf16x8 w1 = *(const bf16x8*)(W + (bc + r1) * K + kt + k0);
        if (kt) __syncthreads();
        *(bf16x8*)(As + r0 * GLDP + k0) = a0;
        *(bf16x8*)(As + r1 * GLDP + k0) = a1;
        *(bf16x8*)(Bs + r0 * GLDP + k0) = w0;
        *(bf16x8*)(Bs + r1 * GLDP + k0) = w1;
        __syncthreads();
        bf16x8 bfr[4];
        #pragma unroll
        for (int j = 0; j < 4; ++j)
            bfr[j] = *(const bf16x8*)(Bs + (wc + j * 16 + l15) * GLDP + q * 8);
        #pragma unroll
        for (int i = 0; i < 4; ++i) {
            bf16x8 afr = *(const bf16x8*)(As + (wr + i * 16 + l15) * GLDP + q * 8);
            #pragma unroll
            for (int j = 0; j < 4; ++j)
                acc[i][j] = __builtin_amdgcn_mfma_f32_16x16x32_bf16(afr, bfr[j], acc[i][j], 0, 0, 0);
        }
    }

    #pragma unroll
    for (int j = 0; j < 4; ++j) {
        int col = (int)bc + wc + j * 16 + l15;
        float bv = bias0[col];
        if (bias1) bv += bias1[col];
        #pragma unroll
        for (int i = 0; i < 4; ++i) {
            int rowb = (int)br + wr + i * 16 + q * 4;
            #pragma unroll
            for (int rr = 0; rr < 4; ++rr) {
                int row = rowb + rr;
                float v = acc[i][j][rr] + bv;
                if (outF) {
                    int orow = permute ? ((row & 63) * T_LEN + (row >> 6)) : row;
                    outF[(size_t)orow * ldo + col] = v;
                } else {
                    outB[(size_t)row * ldo + col] = (bf16_t)v;
                }
            }
        }
    }
}

// ---------------- one LSTM time step, both directions ----------------
// grid: 128 blocks (dir = bid>>6, jb = bid&63), 256 threads (b = tid&63, jj = tid>>6).
// Thread owns (dir, b, j=jb*4+jj): computes 4 gates, updates c (global), h (ping-pong).
__global__ __launch_bounds__(256) void lstm_step_kernel(
    const float* __restrict__ xgf, const float* __restrict__ xgb,   // [NTB][1024]
    const float* __restrict__ Whhf, const float* __restrict__ Whhb, // [1024][256]
    float* __restrict__ hbuf,   // [2 dir][2 ping][64][256]
    float* __restrict__ cbuf,   // [2 dir][256 j][64 b]
    int s,
    bf16_t* __restrict__ h0out, // layer0: [NTB][512] (f|b); null for layer1
    float* __restrict__ finout) // layer1: d_out + 1024, ld 1536, row b*96+t
{
    __shared__ float hs[64 * 256];  // swizzled copy of h_prev (64 KB)
    const int tid = threadIdx.x;
    const int dir = blockIdx.x >> 6, jb = blockIdx.x & 63;
    const int b = tid & 63, jj = tid >> 6;
    const int j = jb * 4 + jj;
    const int t = dir ? (T_LEN - 1 - s) : s;
    const float* xg  = dir ? xgb : xgf;
    const float* Whh = dir ? Whhb : Whhf;
    const float* hprev = hbuf + (size_t)(dir * 2 + (s & 1)) * 64 * 256;
    float* hnext       = hbuf + (size_t)(dir * 2 + ((s + 1) & 1)) * 64 * 256;

    float acc0, acc1, acc2, acc3;
    {
        const float* xr = xg + (size_t)(t * BATCH + b) * 1024 + j;
        acc0 = xr[0]; acc1 = xr[256]; acc2 = xr[512]; acc3 = xr[768];
    }

    if (s > 0) {
        const float4* src = (const float4*)hprev;
        #pragma unroll
        for (int c = 0; c < 16; ++c) {
            int idx4 = c * 256 + tid;
            int bb = idx4 >> 6, kb = idx4 & 63;
            ((float4*)hs)[bb * 64 + (kb ^ (bb & 31))] = src[idx4];
        }
        __syncthreads();
        const float* w0 = Whh + (size_t)(0 * 256 + j) * 256;
        const float* w1 = Whh + (size_t)(1 * 256 + j) * 256;
        const float* w2 = Whh + (size_t)(2 * 256 + j) * 256;
        const float* w3 = Whh + (size_t)(3 * 256 + j) * 256;
        #pragma unroll 4
        for (int kb = 0; kb < 64; ++kb) {
            float4 h4 = ((const float4*)hs)[b * 64 + (kb ^ (b & 31))];
            float4 g0 = ((const float4*)w0)[kb];
            float4 g1 = ((const float4*)w1)[kb];
            float4 g2 = ((const float4*)w2)[kb];
            float4 g3 = ((const float4*)w3)[kb];
            acc0 += h4.x * g0.x + h4.y * g0.y + h4.z * g0.z + h4.w * g0.w;
            acc1 += h4.x * g1.x + h4.y * g1.y + h4.z * g1.z + h4.w * g1.w;
            acc2 += h4.x * g2.x + h4.y * g2.y + h4.z * g2.z + h4.w * g2.w;
            acc3 += h4.x * g3.x + h4.y * g3.y + h4.z * g3.z + h4.w * g3.w;
        }
    }

    float iv = sigmoidf_(acc0);
    float fv = sigmoidf_(acc1);
    float gv = tanhf(acc2);
    float ov = sigmoidf_(acc3);
    const int cidx = (dir * 256 + j) * 64 + b;
    float c = (s == 0) ? (iv * gv) : (fv * cbuf[cidx] + iv * gv);
    cbuf[cidx] = c;
    float h = ov * tanhf(c);
    hnext[b * 256 + j] = h;
    if (h0out) {
        h0out[(size_t)(t * BATCH + b) * 512 + dir * 256 + j] = (bf16_t)h;
    } else {
        finout[(size_t)(b * T_LEN + t) * 1536 + dir * 256 + j] = h;
    }
}

// ---------------- host ----------------
extern "C" void kernel_launch(void* const* d_in, const int* in_sizes, int n_in,
                              void* d_out, int out_size, void* d_ws, size_t ws_size,
                              hipStream_t stream)
{
    const float* r1 = (const float*)d_in[0];
    const float* r2 = (const float*)d_in[1];
    const float* r3 = (const float*)d_in[2];
    const float* r4 = (const float*)d_in[3];
    const float* U_a = (const float*)d_in[4];
    const float* U_v = (const float*)d_in[5];
    const float* W_a = (const float*)d_in[7];
    const float* b_a = (const float*)d_in[8];
    const float* W_v = (const float*)d_in[9];
    const float* b_v = (const float*)d_in[10];
    const float* W_l = (const float*)d_in[11];
    const float* b_l = (const float*)d_in[12];
    const float* Wih0f = (const float*)d_in[13];
    const float* Whh0f = (const float*)d_in[14];
    const float* bih0f = (const float*)d_in[15];
    const float* bhh0f = (const float*)d_in[16];
    const float* Wih0b = (const float*)d_in[17];
    const float* Whh0b = (const float*)d_in[18];
    const float* bih0b = (const float*)d_in[19];
    const float* bhh0b = (const float*)d_in[20];
    const float* Wih1f = (const float*)d_in[21];
    const float* Whh1f = (const float*)d_in[22];
    const float* bih1f = (const float*)d_in[23];
    const float* bhh1f = (const float*)d_in[24];
    const float* Wih1b = (const float*)d_in[25];
    const float* Whh1b = (const float*)d_in[26];
    const float* bih1b = (const float*)d_in[27];
    const float* bhh1b = (const float*)d_in[28];
    float* out = (float*)d_out;

    char* wsb = (char*)d_ws;
    size_t off = 0;
    auto alloc = [&](size_t bytes) -> void* {
        void* p = wsb + off;
        off = (off + bytes + 255) & ~(size_t)255;
        return p;
    };
    float*  stats   = (float*)alloc(512 * sizeof(float));
    bf16_t* Ub      = (bf16_t*)alloc((size_t)NTB * 1024 * 2);
    bf16_t* Uab     = (bf16_t*)alloc((size_t)NTB * 128 * 2);
    bf16_t* Wab     = (bf16_t*)alloc((size_t)512 * 128 * 2);
    bf16_t* Uvb     = (bf16_t*)alloc((size_t)NTB * 512 * 2);
    bf16_t* Wvb     = (bf16_t*)alloc((size_t)512 * 512 * 2);
    bf16_t* Wlb     = (bf16_t*)alloc((size_t)512 * 1024 * 2);
    bf16_t* Wih0fb  = (bf16_t*)alloc((size_t)1024 * 512 * 2);
    bf16_t* Wih0bb  = (bf16_t*)alloc((size_t)1024 * 512 * 2);
    bf16_t* Wih1fb  = (bf16_t*)alloc((size_t)1024 * 512 * 2);
    bf16_t* Wih1bb  = (bf16_t*)alloc((size_t)1024 * 512 * 2);
    bf16_t* Ulb     = (bf16_t*)alloc((size_t)NTB * 512 * 2);
    bf16_t* h0b     = (bf16_t*)alloc((size_t)NTB * 512 * 2);
    float*  xgf     = (float*)alloc((size_t)NTB * 1024 * 4);
    float*  xgb     = (float*)alloc((size_t)NTB * 1024 * 4);
    float*  hbuf    = (float*)alloc((size_t)2 * 2 * 64 * 256 * 4);
    float*  cbuf    = (float*)alloc((size_t)2 * 256 * 64 * 4);

    // LN2 + U
    ln_stats_kernel<<<256, 256, 0, stream>>>(r1, r2, r3, r4, stats);
    compute_u_kernel<<<NTB * 1024 / 4 / 256, 256, 0, stream>>>(r1, r2, r3, r4, stats, Ub);

    // bf16 staging casts
    cast_pad_kernel<<<NTB * 128 / 256, 256, 0, stream>>>(U_a, Uab, NTB, 100, 128);
    cast_pad_kernel<<<512 * 128 / 256, 256, 0, stream>>>(W_a, Wab, 512, 100, 128);
    cast_pad_kernel<<<NTB * 512 / 256, 256, 0, stream>>>(U_v, Uvb, NTB, 512, 512);
    cast_pad_kernel<<<512 * 512 / 256, 256, 0, stream>>>(W_v, Wvb, 512, 512, 512);
    cast_pad_kernel<<<512 * 1024 / 256, 256, 0, stream>>>(W_l, Wlb, 512, 1024, 1024);
    cast_pad_kernel<<<1024 * 512 / 256, 256, 0, stream>>>(Wih0f, Wih0fb, 1024, 512, 512);
    cast_pad_kernel<<<1024 * 512 / 256, 256, 0, stream>>>(Wih0b, Wih0bb, 1024, 512, 512);
    cast_pad_kernel<<<1024 * 512 / 256, 256, 0, stream>>>(Wih1f, Wih1fb, 1024, 512, 512);
    cast_pad_kernel<<<1024 * 512 / 256, 256, 0, stream>>>(Wih1b, Wih1bb, 1024, 512, 512);

    // emotions_a -> out[:, 0:512] ; emotions_v -> out[:, 512:1024]
    gemm_bt_kernel<<<dim3(4, 48), 256, 0, stream>>>(Uab, Wab, b_a, nullptr, 128, out, nullptr, 1536, 1);
    gemm_bt_kernel<<<dim3(4, 48), 256, 0, stream>>>(Uvb, Wvb, b_v, nullptr, 512, out + 512, nullptr, 1536, 1);
    // Ul (bf16, feeds layer0 projections)
    gemm_bt_kernel<<<dim3(4, 48), 256, 0, stream>>>(Ub, Wlb, b_l, nullptr, 1024, nullptr, Ulb, 512, 0);
    // layer0 input projections
    gemm_bt_kernel<<<dim3(8, 48), 256, 0, stream>>>(Ulb, Wih0fb, bih0f, bhh0f, 512, xgf, nullptr, 1024, 0);
    gemm_bt_kernel<<<dim3(8, 48), 256, 0, stream>>>(Ulb, Wih0bb, bih0b, bhh0b, 512, xgb, nullptr, 1024, 0);
    // layer0 recurrence -> h0 (bf16)
    for (int s = 0; s < T_LEN; ++s)
        lstm_step_kernel<<<128, 256, 0, stream>>>(xgf, xgb, Whh0f, Whh0b, hbuf, cbuf, s, h0b, nullptr);
    // layer1 input projections
    gemm_bt_kernel<<<dim3(8, 48), 256, 0, stream>>>(h0b, Wih1fb, bih1f, bhh1f, 512, xgf, nullptr, 1024, 0);
    gemm_bt_kernel<<<dim3(8, 48), 256, 0, stream>>>(h0b, Wih1bb, bih1b, bhh1b, 512, xgb, nullptr, 1024, 0);
    // layer1 recurrence -> out[:, 1024:1536]
    for (int s = 0; s < T_LEN; ++s)
        lstm_step_kernel<<<128, 256, 0, stream>>>(xgf, xgb, Whh1f, Whh1b, hbuf, cbuf, s, nullptr, out + 1024);
}